// Round 1
// baseline (452.805 us; speedup 1.0000x reference)
//
#include <hip/hip_runtime.h>

// Reference is dynamic_partition(data, partitions) followed by
// dynamic_stitch back with the SAME permutation:
//   order = argsort(partitions); out[order[k]] = data[order[k]]
// => out == data exactly (identity). Pure 1 GiB d2d copy, memory-bound.

__global__ __launch_bounds__(256) void copy_f4_kernel(const float4* __restrict__ in,
                                                      float4* __restrict__ out,
                                                      long long n4) {
    long long stride = (long long)gridDim.x * blockDim.x;
    for (long long i = (long long)blockIdx.x * blockDim.x + threadIdx.x; i < n4; i += stride) {
        out[i] = in[i];
    }
}

extern "C" void kernel_launch(void* const* d_in, const int* in_sizes, int n_in,
                              void* d_out, int out_size, void* d_ws, size_t ws_size,
                              hipStream_t stream) {
    const float4* data = (const float4*)d_in[0];
    float4* out = (float4*)d_out;
    long long n = (long long)in_sizes[0];   // 268,435,456 floats (N*D), divisible by 4
    long long n4 = n / 4;

    const int block = 256;
    int grid = 2048;  // 256 CUs * 8 blocks/CU; grid-stride covers the rest
    copy_f4_kernel<<<grid, block, 0, stream>>>(data, out, n4);
}